// Round 1
// 405.433 us; speedup vs baseline: 1.0014x; 1.0014x over previous
//
#include <hip/hip_runtime.h>
#include <hip/hip_bf16.h>
#include <math.h>

#define NTOK 4096
#define HDIM 768
#define FDIM 3072
#define NEXP 4
#define MAXU 3072            // worst-case dropped tokens
#define MAXT 64              // worst-case (expert,mtile) tiles across 8 groups
#define NPOS (NTOK + MAXU)
#define RSTRIDE 76           // repack LDS row stride (shorts): quad bank-bases disjoint

typedef __attribute__((ext_vector_type(4))) float f32x4;
typedef __attribute__((ext_vector_type(8))) short s16x8;

__device__ __forceinline__ unsigned short f2bf(float f) {
    union { float f; unsigned int u; } v; v.f = f;
    unsigned int u = v.u;
    unsigned int r = (u + 0x7fffu + ((u >> 16) & 1u)) >> 16;
    return (unsigned short)r;
}

// async global->LDS, 16B per lane. lds dst is wave-uniform; HW adds lane*16.
__device__ __forceinline__ void gload_lds16(const unsigned short* g, unsigned short* l) {
    __builtin_amdgcn_global_load_lds((const __attribute__((address_space(1))) void*)g,
                                     (__attribute__((address_space(3))) void*)l, 16, 0, 0);
}

// ---------------- routing: one wave per token ------------------------------------
// writes 64-bit sort key: (expert << 32) | float_bits(pmax). pmax in (0,1] so the
// bit pattern is monotonic and bit-equality == float-equality (exact tie semantics).
__global__ void __launch_bounds__(256) route_kernel(
    const float* __restrict__ h, const float* __restrict__ Wsc, const float* __restrict__ bsc,
    const float* __restrict__ Wsu, const float* __restrict__ bsu,
    int* __restrict__ route_c, unsigned long long* __restrict__ key,
    int* __restrict__ route_u, int* __restrict__ counts)
{
    if (blockIdx.x == 0 && threadIdx.x < 8) counts[threadIdx.x] = 0;
    int tok = blockIdx.x * 4 + (threadIdx.x >> 6);
    int lane = threadIdx.x & 63;
    const float* hr = h + (size_t)tok * HDIM;
    float ac[4] = {0.f,0.f,0.f,0.f}, au[4] = {0.f,0.f,0.f,0.f};
    for (int k = lane; k < HDIM; k += 64) {
        float x = hr[k];
        const float4 wc = *(const float4*)(Wsc + k * 4);
        const float4 wu = *(const float4*)(Wsu + k * 4);
        ac[0] += x * wc.x; ac[1] += x * wc.y; ac[2] += x * wc.z; ac[3] += x * wc.w;
        au[0] += x * wu.x; au[1] += x * wu.y; au[2] += x * wu.z; au[3] += x * wu.w;
    }
    #pragma unroll
    for (int off = 32; off > 0; off >>= 1) {
        #pragma unroll
        for (int j = 0; j < 4; ++j) {
            ac[j] += __shfl_xor(ac[j], off);
            au[j] += __shfl_xor(au[j], off);
        }
    }
    if (lane == 0) {
        float lc[4], lu[4];
        #pragma unroll
        for (int j = 0; j < 4; ++j) { lc[j] = ac[j] + bsc[j]; lu[j] = au[j] + bsu[j]; }
        int bc = 0; float mc = lc[0];
        #pragma unroll
        for (int j = 1; j < 4; ++j) if (lc[j] > mc) { mc = lc[j]; bc = j; }
        float dc = 0.f;
        #pragma unroll
        for (int j = 0; j < 4; ++j) dc += expf(lc[j] - mc);
        float p = 1.0f / dc;
        union { float f; unsigned int u; } pv; pv.f = p;
        route_c[tok] = bc;
        key[tok] = ((unsigned long long)(unsigned int)bc << 32) | (unsigned long long)pv.u;
        int bu = 0; float mu = lu[0];
        #pragma unroll
        for (int j = 1; j < 4; ++j) if (lu[j] > mu) { mu = lu[j]; bu = j; }
        route_u[tok] = bu;
    }
}

// ------- rank within expert group by (-pmax, index) ------------------------------
// LDS-staged branch-free scan: block stages all 4096 keys (32 KB) once, each wave
// ranks 4 tokens (one ds_read_b64 amortized over 4 predicated compares).
__global__ void __launch_bounds__(256) rank_kernel(
    const unsigned long long* __restrict__ key, const int* __restrict__ ru,
    int* __restrict__ dropped, int* __restrict__ counts, int capacity)
{
    __shared__ unsigned long long lkey[NTOK];
    int tid = threadIdx.x;
    int wave = tid >> 6, lane = tid & 63;

    // stage key array into LDS (16B per thread per iter, coalesced)
    const ulonglong2* k2 = (const ulonglong2*)key;
    ulonglong2* l2 = (ulonglong2*)lkey;
    #pragma unroll
    for (int j = 0; j < NTOK / 2 / 256; ++j)
        l2[tid + j * 256] = k2[tid + j * 256];

    int t0 = blockIdx.x * 16 + wave * 4;      // 4 tokens per wave
    unsigned long long ki[4];
    int cnt[4] = {0, 0, 0, 0};
    #pragma unroll
    for (int t = 0; t < 4; ++t) ki[t] = key[t0 + t];

    __syncthreads();

    for (int it = 0; it < NTOK / 64; ++it) {
        int j = lane + it * 64;
        unsigned long long kj = lkey[j];
        #pragma unroll
        for (int t = 0; t < 4; ++t) {
            bool same = ((kj ^ ki[t]) >> 32) == 0;                      // same expert
            bool hi = (kj > ki[t]) || ((kj == ki[t]) && (j < t0 + t));  // higher priority
            cnt[t] += (same && hi) ? 1 : 0;
        }
    }
    #pragma unroll
    for (int off = 32; off > 0; off >>= 1) {
        #pragma unroll
        for (int t = 0; t < 4; ++t) cnt[t] += __shfl_xor(cnt[t], off);
    }
    if (lane == 0) {
        #pragma unroll
        for (int t = 0; t < 4; ++t) {
            int i = t0 + t;
            int d = (cnt[t] >= capacity) ? 1 : 0;
            dropped[i] = d;
            atomicAdd(&counts[(int)(ki[t] >> 32)], 1);
            if (d) atomicAdd(&counts[4 + ru[i]], 1);
        }
    }
}

// offsets for 8 groups (4 common + 4 unique), tile table, ntot
__global__ void offsets_kernel(const int* __restrict__ counts,
                               int* __restrict__ offAll,  // 9
                               int* __restrict__ cur,     // 8
                               int* __restrict__ tab,     // MAXT*2
                               int* __restrict__ ntot)
{
    if (threadIdx.x == 0 && blockIdx.x == 0) {
        int o = 0;
        for (int e = 0; e < 8; ++e) { offAll[e] = o; o += counts[e]; }
        offAll[8] = o;
        *ntot = o;
        for (int j = 0; j < 8; ++j) cur[j] = 0;
        int t = 0;
        for (int e = 0; e < 8; ++e) {
            int nt = (counts[e] + 127) >> 7;
            for (int m = 0; m < nt && t < MAXT; ++m) { tab[t*2] = e; tab[t*2+1] = m; ++t; }
        }
        for (; t < MAXT; ++t) { tab[t*2] = -1; tab[t*2+1] = 0; }
    }
}

__global__ void __launch_bounds__(256) scatter_kernel(
    const int* __restrict__ rc, const int* __restrict__ ru, const int* __restrict__ dropped,
    const int* __restrict__ offAll, int* __restrict__ cur, int* __restrict__ perm,
    int* __restrict__ invC, int* __restrict__ invU)
{
    int i = blockIdx.x * 256 + threadIdx.x;
    if (i >= NTOK) return;
    int e = rc[i];
    int p = offAll[e] + atomicAdd(&cur[e], 1);
    perm[p] = i;
    invC[i] = p;
    if (dropped[i]) {
        int eu = 4 + ru[i];
        int q = offAll[eu] + atomicAdd(&cur[eu], 1);
        perm[q] = i;
        invU[i] = q;
    }
}

// ---------------- gather tokens (sorted order) into bf16 -------------------------
__global__ void __launch_bounds__(192) gather_kernel(
    const float* __restrict__ h, const int* __restrict__ perm,
    const int* __restrict__ ntot, unsigned short* __restrict__ Xs)
{
    int pos = blockIdx.x;
    if (pos >= *ntot) return;
    int t = threadIdx.x;
    int tok = perm[pos];
    const float4 v = *(const float4*)(h + (size_t)tok * HDIM + t * 4);
    ushort4 o;
    o.x = f2bf(v.x); o.y = f2bf(v.y); o.z = f2bf(v.z); o.w = f2bf(v.w);
    *(ushort4*)(Xs + (size_t)pos * HDIM + t * 4) = o;
}

// ------- weight transpose+convert: fp32 [4][K][N] x2 -> bf16 [8][N][K] -----------
// 128k x 64n tile: reads float4 coalesced, writes 256-B contiguous k-segments.
__global__ void __launch_bounds__(256) wtrans_kernel(
    const float* __restrict__ Wc, const float* __restrict__ Wu,
    unsigned short* __restrict__ Bt, int K, int N)
{
    int z = blockIdx.z;   // 0..7
    const float* We = (z < 4) ? (Wc + (size_t)z * K * N)
                              : (Wu + (size_t)(z - 4) * K * N);
    unsigned short* Be = Bt + (size_t)z * N * K;
    int k0 = blockIdx.y * 128, n0 = blockIdx.x * 64;
    __shared__ float t[128][65];
    int tid = threadIdx.x;
    int rr = tid >> 4, c4 = (tid & 15) * 4;   // 16 float4 per 64-float row
    #pragma unroll
    for (int i = 0; i < 8; ++i) {
        int row = rr + i * 16;
        const float4 v = *(const float4*)(We + (size_t)(k0 + row) * N + n0 + c4);
        t[row][c4+0] = v.x; t[row][c4+1] = v.y; t[row][c4+2] = v.z; t[row][c4+3] = v.w;
    }
    __syncthreads();
    #pragma unroll
    for (int i = 0; i < 8; ++i) {
        int idx = tid + i * 256;
        int n = idx >> 5, kk = (idx & 31) * 4;   // 32 ushort4 per 128-k row
        ushort4 o;
        o.x = f2bf(t[kk+0][n]); o.y = f2bf(t[kk+1][n]);
        o.z = f2bf(t[kk+2][n]); o.w = f2bf(t[kk+3][n]);
        *(ushort4*)(Be + (size_t)(n0 + n) * K + k0 + kk) = o;
    }
}

// ---------------- grouped GEMM over 8 groups, 128(M)x64(N), BK=64 ----------------
// LDS staging via global_load_lds, 3-bit XOR chunk swizzle; wave tile 32x64.
//  doGelu=1: GELU -> wave-private LDS repack -> ushort4 full-line stores to Gout[pos]
//  doGelu=0: fp32 stores into per-z slab Yout[z][pos][N] (no atomics)
__global__ void __launch_bounds__(256, 4) ffn_gemm(
    const unsigned short* __restrict__ A, const unsigned short* __restrict__ Bt,
    const float* __restrict__ biasC, const float* __restrict__ biasU,
    const int* __restrict__ offs, const int* __restrict__ tab,
    unsigned short* __restrict__ Gout, float* __restrict__ Yout,
    int K, int N, int doGelu)
{
    int e = tab[blockIdx.y * 2];
    if (e < 0) return;
    int mt = tab[blockIdx.y * 2 + 1];
    int off = offs[e];
    int cnt = offs[e + 1] - off;
    if (mt * 128 >= cnt) return;
    int nt = blockIdx.x;
    int klen = K / gridDim.z;
    int kbeg = blockIdx.z * klen;

    // LDS: As 128r x 64k bf16 = [0,8192) shorts; Bs 64r x 64k = [8192,12288).
    // chunk (row,s) s=0..7 holds global k-seg (s ^ (row&7)); chunk c at base c*8.
    // FFN1 epilogue repack reuses [0, 4*32*RSTRIDE)=9728 shorts.
    __shared__ unsigned short lds[12288];
    unsigned short* As = lds;
    unsigned short* Bs = lds + 8192;

    int tid = threadIdx.x;
    int lane = tid & 63, wave = tid >> 6;
    int quad = lane >> 4, l16 = lane & 15;

    f32x4 acc[2][4];
    #pragma unroll
    for (int a = 0; a < 2; ++a)
        #pragma unroll
        for (int b = 0; b < 4; ++b)
            acc[a][b] = (f32x4){0.f, 0.f, 0.f, 0.f};

    const unsigned short* Ae = A + (size_t)off * K;
    const unsigned short* Be = Bt + ((size_t)e * N + (size_t)nt * 64) * K;

    // A: 1024 chunks, 4 per thread; B: 512 chunks, 2 per thread
    const unsigned short* asrc[4]; unsigned short* adst[4];
    #pragma unroll
    for (int j = 0; j < 4; ++j) {
        int c = tid + j * 256;
        int row = c >> 3, s = c & 7;
        int gseg = (s ^ (row & 7)) * 8;
        int ar = mt * 128 + row; if (ar >= cnt) ar = cnt - 1;
        asrc[j] = Ae + (size_t)ar * K + kbeg + gseg;
        adst[j] = &As[(j * 256 + wave * 64) * 8];   // wave-uniform; HW adds lane*16B
    }
    const unsigned short* bsrc[2]; unsigned short* bdst[2];
    #pragma unroll
    for (int j = 0; j < 2; ++j) {
        int c = tid + j * 256;
        int row = c >> 3, s = c & 7;
        int gseg = (s ^ (row & 7)) * 8;
        bsrc[j] = Be + (size_t)row * K + kbeg + gseg;
        bdst[j] = &Bs[(j * 256 + wave * 64) * 8];
    }

    for (int k0 = 0; k0 < klen; k0 += 64) {
        #pragma unroll
        for (int j = 0; j < 4; ++j) gload_lds16(asrc[j] + k0, adst[j]);
        #pragma unroll
        for (int j = 0; j < 2; ++j) gload_lds16(bsrc[j] + k0, bdst[j]);
        __syncthreads();

        #pragma unroll
        for (int ks = 0; ks < 2; ++ks) {
            int cc = ((ks * 4 + quad) ^ (l16 & 7)) * 8;
            s16x8 af[2], bf[4];
            #pragma unroll
            for (int mi = 0; mi < 2; ++mi)
                af[mi] = *(const s16x8*)&As[(wave * 32 + mi * 16 + l16) * 64 + cc];
            #pragma unroll
            for (int ni = 0; ni < 4; ++ni)
                bf[ni] = *(const s16x8*)&Bs[(ni * 16 + l16) * 64 + cc];
            #pragma unroll
            for (int mi = 0; mi < 2; ++mi)
                #pragma unroll
                for (int ni = 0; ni < 4; ++ni)
                    acc[mi][ni] = __builtin_amdgcn_mfma_f32_16x16x32_bf16(af[mi], bf[ni], acc[mi][ni], 0, 0, 0);
        }
        __syncthreads();
    }

    const float* bias = (e < 4) ? (biasC + (size_t)e * N) : (biasU + (size_t)(e - 4) * N);

    if (doGelu) {
        // GELU + bf16, repack 32x64 wave tile via wave-private LDS, 8B/lane stores
        unsigned short* R = lds + wave * (32 * RSTRIDE);
        #pragma unroll
        for (int ni = 0; ni < 4; ++ni) {
            float bv = bias[nt * 64 + ni * 16 + l16];
            #pragma unroll
            for (int mi = 0; mi < 2; ++mi) {
                #pragma unroll
                for (int r = 0; r < 4; ++r) {
                    float x = acc[mi][ni][r] + bv;
                    x = 0.5f * x * (1.0f + erff(x * 0.70710678118654752440f));
                    R[(mi * 16 + quad * 4 + r) * RSTRIDE + ni * 16 + l16] = f2bf(x);
                }
            }
        }
        __builtin_amdgcn_s_waitcnt(0);  // wave-private region: no barrier needed
        int lrow = lane >> 4, lcol = (lane & 15) * 4;
        #pragma unroll
        for (int p = 0; p < 8; ++p) {
            int row = p * 4 + lrow;
            int gr = mt * 128 + wave * 32 + row;
            if (gr < cnt) {
                ushort4 v = *(const ushort4*)&R[row * RSTRIDE + lcol];
                *(ushort4*)&Gout[(size_t)(off + gr) * N + nt * 64 + lcol] = v;
            }
        }
    } else {
        float* Yz = Yout + (size_t)blockIdx.z * NPOS * N;
        #pragma unroll
        for (int ni = 0; ni < 4; ++ni) {
            int col = nt * 64 + ni * 16 + l16;
            float bv = (blockIdx.z == 0) ? bias[col] : 0.f;
            #pragma unroll
            for (int mi = 0; mi < 2; ++mi) {
                #pragma unroll
                for (int r = 0; r < 4; ++r) {
                    int lm = mt * 128 + wave * 32 + mi * 16 + quad * 4 + r;
                    if (lm < cnt)
                        Yz[(size_t)(off + lm) * N + col] = acc[mi][ni][r] + bv;
                }
            }
        }
    }
}

// ---------------- combine: out[tok] = sum_z Y[z][posC] + dropped * sum_z Y[z][posU]
__global__ void __launch_bounds__(192) combine_kernel(
    const float* __restrict__ Y, const int* __restrict__ invC,
    const int* __restrict__ invU, const int* __restrict__ dropped,
    float* __restrict__ out)
{
    int tok = blockIdx.x, t = threadIdx.x;
    const float* Y0 = Y;
    const float* Y1 = Y + (size_t)NPOS * HDIM;
    int pc = invC[tok];
    float4 a = *(const float4*)(Y0 + (size_t)pc * HDIM + t * 4);
    float4 b = *(const float4*)(Y1 + (size_t)pc * HDIM + t * 4);
    float4 o;
    o.x = a.x + b.x; o.y = a.y + b.y; o.z = a.z + b.z; o.w = a.w + b.w;
    if (dropped[tok]) {
        int pu = invU[tok];
        float4 c = *(const float4*)(Y0 + (size_t)pu * HDIM + t * 4);
        float4 d = *(const float4*)(Y1 + (size_t)pu * HDIM + t * 4);
        o.x += c.x + d.x; o.y += c.y + d.y; o.z += c.z + d.z; o.w += c.w + d.w;
    }
    *(float4*)(out + (size_t)tok * HDIM + t * 4) = o;
}

extern "C" void kernel_launch(void* const* d_in, const int* in_sizes, int n_in,
                              void* d_out, int out_size, void* d_ws, size_t ws_size,
                              hipStream_t stream) {
    (void)in_sizes; (void)n_in; (void)out_size; (void)ws_size;
    const float* h   = (const float*)d_in[0];
    const float* Wsc = (const float*)d_in[1];
    const float* bsc = (const float*)d_in[2];
    const float* W1c = (const float*)d_in[3];
    const float* b1c = (const float*)d_in[4];
    const float* W2c = (const float*)d_in[5];
    const float* b2c = (const float*)d_in[6];
    const float* Wsu = (const float*)d_in[7];
    const float* bsu = (const float*)d_in[8];
    const float* W1u = (const float*)d_in[9];
    const float* b1u = (const float*)d_in[10];
    const float* W2u = (const float*)d_in[11];
    const float* b2u = (const float*)d_in[12];
    float* out = (float*)d_out;

    char* w = (char*)d_ws;
    size_t o = 0;
    auto carve = [&](size_t bytes) -> char* {
        char* p = w + o; o += (bytes + 255) & ~(size_t)255; return p;
    };
    int*   route_c = (int*)carve(NTOK * 4);
    unsigned long long* key = (unsigned long long*)carve(NTOK * 8);
    int*   route_u = (int*)carve(NTOK * 4);
    int*   dropped = (int*)carve(NTOK * 4);
    int*   counts  = (int*)carve(8 * 4);
    int*   offAll  = (int*)carve(9 * 4);
    int*   cur     = (int*)carve(8 * 4);
    int*   ntot    = (int*)carve(4);
    int*   perm    = (int*)carve(NPOS * 4);
    int*   invC    = (int*)carve(NTOK * 4);
    int*   invU    = (int*)carve(NTOK * 4);
    int*   tab     = (int*)carve(MAXT * 2 * 4);
    unsigned short* X   = (unsigned short*)carve((size_t)NPOS * HDIM * 2);
    unsigned short* G   = (unsigned short*)carve((size_t)NPOS * FDIM * 2);
    float*          Y2  = (float*)carve((size_t)2 * NPOS * HDIM * 4);
    unsigned short* BtA = (unsigned short*)carve((size_t)8 * HDIM * FDIM * 2);
    unsigned short* BtB = (unsigned short*)carve((size_t)8 * FDIM * HDIM * 2);

    int capacity = NTOK / NEXP;   // int(1.0 * 4096 / 4) = 1024

    route_kernel<<<NTOK/4, 256, 0, stream>>>(h, Wsc, bsc, Wsu, bsu,
                                             route_c, key, route_u, counts);
    rank_kernel<<<NTOK/16, 256, 0, stream>>>(key, route_u, dropped, counts, capacity);
    offsets_kernel<<<1, 64, 0, stream>>>(counts, offAll, cur, tab, ntot);
    scatter_kernel<<<NTOK/256, 256, 0, stream>>>(route_c, route_u, dropped,
                                                 offAll, cur, perm, invC, invU);
    gather_kernel<<<NPOS, 192, 0, stream>>>(h, perm, ntot, X);

    // transpose+convert weights to bf16 [8][N][K] (c experts z<4, u experts z>=4)
    wtrans_kernel<<<dim3(FDIM/64, HDIM/128, 8), 256, 0, stream>>>(W1c, W1u, BtA, HDIM, FDIM);
    wtrans_kernel<<<dim3(HDIM/64, FDIM/128, 8), 256, 0, stream>>>(W2c, W2u, BtB, FDIM, HDIM);

    // FFN1 over 8 groups: X @ W1 -> GELU -> G (bf16, position-indexed)
    ffn_gemm<<<dim3(FDIM/64, MAXT, 1), 256, 0, stream>>>(
        X, BtA, b1c, b1u, offAll, tab, G, nullptr, HDIM, FDIM, 1);
    // FFN2: G @ W2 -> Y2[z][pos][H] (fp32 slabs, split-K=2, no atomics)
    ffn_gemm<<<dim3(HDIM/64, MAXT, 2), 256, 0, stream>>>(
        G, BtB, b2c, b2u, offAll, tab, nullptr, Y2, FDIM, HDIM, 0);
    // out[tok] = sum of slabs at common pos (+ unique pos if dropped)
    combine_kernel<<<NTOK, 192, 0, stream>>>(Y2, invC, invU, dropped, out);
}

// Round 2
// 340.177 us; speedup vs baseline: 1.1935x; 1.1918x over previous
//
#include <hip/hip_runtime.h>
#include <hip/hip_bf16.h>
#include <math.h>

#define NTOK 4096
#define HDIM 768
#define FDIM 3072
#define NEXP 4
#define MAXU 3072            // worst-case dropped tokens
#define MAXT 64              // worst-case (expert,mtile) tiles across 8 groups
#define NPOS (NTOK + MAXU)
#define RSTRIDE 76           // repack LDS row stride (shorts): quad bank-bases disjoint

typedef __attribute__((ext_vector_type(4))) float f32x4;
typedef __attribute__((ext_vector_type(8))) short s16x8;

__device__ __forceinline__ unsigned short f2bf(float f) {
    union { float f; unsigned int u; } v; v.f = f;
    unsigned int u = v.u;
    unsigned int r = (u + 0x7fffu + ((u >> 16) & 1u)) >> 16;
    return (unsigned short)r;
}

// async global->LDS, 16B per lane. lds dst is wave-uniform; HW adds lane*16.
__device__ __forceinline__ void gload_lds16(const unsigned short* g, unsigned short* l) {
    __builtin_amdgcn_global_load_lds((const __attribute__((address_space(1))) void*)g,
                                     (__attribute__((address_space(3))) void*)l, 16, 0, 0);
}

// ---------------- routing: one wave per token ------------------------------------
// writes 64-bit sort key: (expert << 32) | float_bits(pmax). pmax in (0,1] so the
// bit pattern is monotonic and bit-equality == float-equality (exact tie semantics).
__global__ void __launch_bounds__(256) route_kernel(
    const float* __restrict__ h, const float* __restrict__ Wsc, const float* __restrict__ bsc,
    const float* __restrict__ Wsu, const float* __restrict__ bsu,
    int* __restrict__ route_c, unsigned long long* __restrict__ key,
    int* __restrict__ route_u)
{
    int tok = blockIdx.x * 4 + (threadIdx.x >> 6);
    int lane = threadIdx.x & 63;
    const float* hr = h + (size_t)tok * HDIM;
    float ac[4] = {0.f,0.f,0.f,0.f}, au[4] = {0.f,0.f,0.f,0.f};
    for (int k = lane; k < HDIM; k += 64) {
        float x = hr[k];
        const float4 wc = *(const float4*)(Wsc + k * 4);
        const float4 wu = *(const float4*)(Wsu + k * 4);
        ac[0] += x * wc.x; ac[1] += x * wc.y; ac[2] += x * wc.z; ac[3] += x * wc.w;
        au[0] += x * wu.x; au[1] += x * wu.y; au[2] += x * wu.z; au[3] += x * wu.w;
    }
    #pragma unroll
    for (int off = 32; off > 0; off >>= 1) {
        #pragma unroll
        for (int j = 0; j < 4; ++j) {
            ac[j] += __shfl_xor(ac[j], off);
            au[j] += __shfl_xor(au[j], off);
        }
    }
    if (lane == 0) {
        float lc[4], lu[4];
        #pragma unroll
        for (int j = 0; j < 4; ++j) { lc[j] = ac[j] + bsc[j]; lu[j] = au[j] + bsu[j]; }
        int bc = 0; float mc = lc[0];
        #pragma unroll
        for (int j = 1; j < 4; ++j) if (lc[j] > mc) { mc = lc[j]; bc = j; }
        float dc = 0.f;
        #pragma unroll
        for (int j = 0; j < 4; ++j) dc += expf(lc[j] - mc);
        float p = 1.0f / dc;
        union { float f; unsigned int u; } pv; pv.f = p;
        route_c[tok] = bc;
        key[tok] = ((unsigned long long)(unsigned int)bc << 32) | (unsigned long long)pv.u;
        int bu = 0; float mu = lu[0];
        #pragma unroll
        for (int j = 1; j < 4; ++j) if (lu[j] > mu) { mu = lu[j]; bu = j; }
        route_u[tok] = bu;
    }
}

// ------- rank within expert group by (-pmax, index) ------------------------------
// LDS-staged branch-free scan. cnt = #{same-expert tokens with higher priority}
// is a collision-free position within the expert group (strict total order),
// so it doubles as the scatter position -> NO global atomics anywhere here.
__global__ void __launch_bounds__(256) rank_kernel(
    const unsigned long long* __restrict__ key,
    int* __restrict__ rankC, int* __restrict__ dropped, int capacity)
{
    __shared__ unsigned long long lkey[NTOK];
    int tid = threadIdx.x;
    int wave = tid >> 6, lane = tid & 63;

    // stage key array into LDS (16B per thread per iter, coalesced)
    const ulonglong2* k2 = (const ulonglong2*)key;
    ulonglong2* l2 = (ulonglong2*)lkey;
    #pragma unroll
    for (int j = 0; j < NTOK / 2 / 256; ++j)
        l2[tid + j * 256] = k2[tid + j * 256];

    int t0 = blockIdx.x * 16 + wave * 4;      // 4 tokens per wave
    unsigned long long ki[4];
    int cnt[4] = {0, 0, 0, 0};
    #pragma unroll
    for (int t = 0; t < 4; ++t) ki[t] = key[t0 + t];

    __syncthreads();

    for (int it = 0; it < NTOK / 64; ++it) {
        int j = lane + it * 64;
        unsigned long long kj = lkey[j];
        #pragma unroll
        for (int t = 0; t < 4; ++t) {
            bool same = ((kj ^ ki[t]) >> 32) == 0;                      // same expert
            bool hi = (kj > ki[t]) || ((kj == ki[t]) && (j < t0 + t));  // higher priority
            cnt[t] += (same && hi) ? 1 : 0;
        }
    }
    #pragma unroll
    for (int off = 32; off > 0; off >>= 1) {
        #pragma unroll
        for (int t = 0; t < 4; ++t) cnt[t] += __shfl_xor(cnt[t], off);
    }
    if (lane == 0) {
        #pragma unroll
        for (int t = 0; t < 4; ++t) {
            int i = t0 + t;
            rankC[i] = cnt[t];
            dropped[i] = (cnt[t] >= capacity) ? 1 : 0;
        }
    }
}

// --------- fused histogram + offsets + tile table (one 256-thread block) ---------
// register histogram (branch-free), wave shuffle-reduce, 32 LDS atomics total.
__global__ void __launch_bounds__(256) offsets_kernel(
    const int* __restrict__ rc, const int* __restrict__ ru, const int* __restrict__ dropped,
    int* __restrict__ offAll,  // 9
    int* __restrict__ cur,     // 8
    int* __restrict__ tab,     // MAXT*2
    int* __restrict__ ntot)
{
    __shared__ int sc[8];
    int tid = threadIdx.x;
    if (tid < 8) sc[tid] = 0;
    int c0=0,c1=0,c2=0,c3=0,c4=0,c5=0,c6=0,c7=0;
    #pragma unroll
    for (int j = 0; j < NTOK / 256; ++j) {
        int i = tid + j * 256;
        int e = rc[i];
        c0 += (e == 0); c1 += (e == 1); c2 += (e == 2); c3 += (e == 3);
        int d = dropped[i];
        int eu = ru[i];
        c4 += d & (eu == 0); c5 += d & (eu == 1);
        c6 += d & (eu == 2); c7 += d & (eu == 3);
    }
    #pragma unroll
    for (int off = 32; off > 0; off >>= 1) {
        c0 += __shfl_xor(c0, off); c1 += __shfl_xor(c1, off);
        c2 += __shfl_xor(c2, off); c3 += __shfl_xor(c3, off);
        c4 += __shfl_xor(c4, off); c5 += __shfl_xor(c5, off);
        c6 += __shfl_xor(c6, off); c7 += __shfl_xor(c7, off);
    }
    __syncthreads();
    if ((tid & 63) == 0) {
        atomicAdd(&sc[0], c0); atomicAdd(&sc[1], c1);
        atomicAdd(&sc[2], c2); atomicAdd(&sc[3], c3);
        atomicAdd(&sc[4], c4); atomicAdd(&sc[5], c5);
        atomicAdd(&sc[6], c6); atomicAdd(&sc[7], c7);
    }
    __syncthreads();
    if (tid == 0) {
        int o = 0;
        for (int e = 0; e < 8; ++e) { offAll[e] = o; o += sc[e]; }
        offAll[8] = o;
        *ntot = o;
        for (int j = 0; j < 8; ++j) cur[j] = 0;
        int t = 0;
        for (int e = 0; e < 8; ++e) {
            int nt = (sc[e] + 127) >> 7;
            for (int m = 0; m < nt && t < MAXT; ++m) { tab[t*2] = e; tab[t*2+1] = m; ++t; }
        }
        for (; t < MAXT; ++t) { tab[t*2] = -1; tab[t*2+1] = 0; }
    }
}

// ----- scatter: common position is deterministic (offAll[e] + rank) -------------
// atomics only for dropped tokens (~tens) -> negligible contention.
__global__ void __launch_bounds__(256) scatter_kernel(
    const int* __restrict__ rc, const int* __restrict__ ru, const int* __restrict__ dropped,
    const int* __restrict__ rankC,
    const int* __restrict__ offAll, int* __restrict__ cur, int* __restrict__ perm,
    int* __restrict__ invC, int* __restrict__ invU)
{
    int i = blockIdx.x * 256 + threadIdx.x;
    if (i >= NTOK) return;
    int e = rc[i];
    int p = offAll[e] + rankC[i];
    perm[p] = i;
    invC[i] = p;
    if (dropped[i]) {
        int eu = 4 + ru[i];
        int q = offAll[eu] + atomicAdd(&cur[eu], 1);
        perm[q] = i;
        invU[i] = q;
    }
}

// ---------------- gather tokens (sorted order) into bf16 -------------------------
__global__ void __launch_bounds__(192) gather_kernel(
    const float* __restrict__ h, const int* __restrict__ perm,
    const int* __restrict__ ntot, unsigned short* __restrict__ Xs)
{
    int pos = blockIdx.x;
    if (pos >= *ntot) return;
    int t = threadIdx.x;
    int tok = perm[pos];
    const float4 v = *(const float4*)(h + (size_t)tok * HDIM + t * 4);
    ushort4 o;
    o.x = f2bf(v.x); o.y = f2bf(v.y); o.z = f2bf(v.z); o.w = f2bf(v.w);
    *(ushort4*)(Xs + (size_t)pos * HDIM + t * 4) = o;
}

// ------- weight transpose+convert: fp32 [4][K][N] x2 -> bf16 [8][N][K] -----------
// 128k x 64n tile: reads float4 coalesced, writes 256-B contiguous k-segments.
__global__ void __launch_bounds__(256) wtrans_kernel(
    const float* __restrict__ Wc, const float* __restrict__ Wu,
    unsigned short* __restrict__ Bt, int K, int N)
{
    int z = blockIdx.z;   // 0..7
    const float* We = (z < 4) ? (Wc + (size_t)z * K * N)
                              : (Wu + (size_t)(z - 4) * K * N);
    unsigned short* Be = Bt + (size_t)z * N * K;
    int k0 = blockIdx.y * 128, n0 = blockIdx.x * 64;
    __shared__ float t[128][65];
    int tid = threadIdx.x;
    int rr = tid >> 4, c4 = (tid & 15) * 4;   // 16 float4 per 64-float row
    #pragma unroll
    for (int i = 0; i < 8; ++i) {
        int row = rr + i * 16;
        const float4 v = *(const float4*)(We + (size_t)(k0 + row) * N + n0 + c4);
        t[row][c4+0] = v.x; t[row][c4+1] = v.y; t[row][c4+2] = v.z; t[row][c4+3] = v.w;
    }
    __syncthreads();
    #pragma unroll
    for (int i = 0; i < 8; ++i) {
        int idx = tid + i * 256;
        int n = idx >> 5, kk = (idx & 31) * 4;   // 32 ushort4 per 128-k row
        ushort4 o;
        o.x = f2bf(t[kk+0][n]); o.y = f2bf(t[kk+1][n]);
        o.z = f2bf(t[kk+2][n]); o.w = f2bf(t[kk+3][n]);
        *(ushort4*)(Be + (size_t)(n0 + n) * K + k0 + kk) = o;
    }
}

// ---------------- grouped GEMM over 8 groups, 128(M)x64(N), BK=64 ----------------
// LDS staging via global_load_lds, 3-bit XOR chunk swizzle; wave tile 32x64.
//  doGelu=1: GELU -> wave-private LDS repack -> ushort4 full-line stores to Gout[pos]
//  doGelu=0: fp32 stores into per-z slab Yout[z][pos][N] (no atomics)
__global__ void __launch_bounds__(256, 4) ffn_gemm(
    const unsigned short* __restrict__ A, const unsigned short* __restrict__ Bt,
    const float* __restrict__ biasC, const float* __restrict__ biasU,
    const int* __restrict__ offs, const int* __restrict__ tab,
    unsigned short* __restrict__ Gout, float* __restrict__ Yout,
    int K, int N, int doGelu)
{
    int e = tab[blockIdx.y * 2];
    if (e < 0) return;
    int mt = tab[blockIdx.y * 2 + 1];
    int off = offs[e];
    int cnt = offs[e + 1] - off;
    if (mt * 128 >= cnt) return;
    int nt = blockIdx.x;
    int klen = K / gridDim.z;
    int kbeg = blockIdx.z * klen;

    // LDS: As 128r x 64k bf16 = [0,8192) shorts; Bs 64r x 64k = [8192,12288).
    // chunk (row,s) s=0..7 holds global k-seg (s ^ (row&7)); chunk c at base c*8.
    // FFN1 epilogue repack reuses [0, 4*32*RSTRIDE)=9728 shorts.
    __shared__ unsigned short lds[12288];
    unsigned short* As = lds;
    unsigned short* Bs = lds + 8192;

    int tid = threadIdx.x;
    int lane = tid & 63, wave = tid >> 6;
    int quad = lane >> 4, l16 = lane & 15;

    f32x4 acc[2][4];
    #pragma unroll
    for (int a = 0; a < 2; ++a)
        #pragma unroll
        for (int b = 0; b < 4; ++b)
            acc[a][b] = (f32x4){0.f, 0.f, 0.f, 0.f};

    const unsigned short* Ae = A + (size_t)off * K;
    const unsigned short* Be = Bt + ((size_t)e * N + (size_t)nt * 64) * K;

    // A: 1024 chunks, 4 per thread; B: 512 chunks, 2 per thread
    const unsigned short* asrc[4]; unsigned short* adst[4];
    #pragma unroll
    for (int j = 0; j < 4; ++j) {
        int c = tid + j * 256;
        int row = c >> 3, s = c & 7;
        int gseg = (s ^ (row & 7)) * 8;
        int ar = mt * 128 + row; if (ar >= cnt) ar = cnt - 1;
        asrc[j] = Ae + (size_t)ar * K + kbeg + gseg;
        adst[j] = &As[(j * 256 + wave * 64) * 8];   // wave-uniform; HW adds lane*16B
    }
    const unsigned short* bsrc[2]; unsigned short* bdst[2];
    #pragma unroll
    for (int j = 0; j < 2; ++j) {
        int c = tid + j * 256;
        int row = c >> 3, s = c & 7;
        int gseg = (s ^ (row & 7)) * 8;
        bsrc[j] = Be + (size_t)row * K + kbeg + gseg;
        bdst[j] = &Bs[(j * 256 + wave * 64) * 8];
    }

    for (int k0 = 0; k0 < klen; k0 += 64) {
        #pragma unroll
        for (int j = 0; j < 4; ++j) gload_lds16(asrc[j] + k0, adst[j]);
        #pragma unroll
        for (int j = 0; j < 2; ++j) gload_lds16(bsrc[j] + k0, bdst[j]);
        __syncthreads();

        #pragma unroll
        for (int ks = 0; ks < 2; ++ks) {
            int cc = ((ks * 4 + quad) ^ (l16 & 7)) * 8;
            s16x8 af[2], bf[4];
            #pragma unroll
            for (int mi = 0; mi < 2; ++mi)
                af[mi] = *(const s16x8*)&As[(wave * 32 + mi * 16 + l16) * 64 + cc];
            #pragma unroll
            for (int ni = 0; ni < 4; ++ni)
                bf[ni] = *(const s16x8*)&Bs[(ni * 16 + l16) * 64 + cc];
            #pragma unroll
            for (int mi = 0; mi < 2; ++mi)
                #pragma unroll
                for (int ni = 0; ni < 4; ++ni)
                    acc[mi][ni] = __builtin_amdgcn_mfma_f32_16x16x32_bf16(af[mi], bf[ni], acc[mi][ni], 0, 0, 0);
        }
        __syncthreads();
    }

    const float* bias = (e < 4) ? (biasC + (size_t)e * N) : (biasU + (size_t)(e - 4) * N);

    if (doGelu) {
        // GELU + bf16, repack 32x64 wave tile via wave-private LDS, 8B/lane stores
        unsigned short* R = lds + wave * (32 * RSTRIDE);
        #pragma unroll
        for (int ni = 0; ni < 4; ++ni) {
            float bv = bias[nt * 64 + ni * 16 + l16];
            #pragma unroll
            for (int mi = 0; mi < 2; ++mi) {
                #pragma unroll
                for (int r = 0; r < 4; ++r) {
                    float x = acc[mi][ni][r] + bv;
                    x = 0.5f * x * (1.0f + erff(x * 0.70710678118654752440f));
                    R[(mi * 16 + quad * 4 + r) * RSTRIDE + ni * 16 + l16] = f2bf(x);
                }
            }
        }
        __builtin_amdgcn_s_waitcnt(0);  // wave-private region: no barrier needed
        int lrow = lane >> 4, lcol = (lane & 15) * 4;
        #pragma unroll
        for (int p = 0; p < 8; ++p) {
            int row = p * 4 + lrow;
            int gr = mt * 128 + wave * 32 + row;
            if (gr < cnt) {
                ushort4 v = *(const ushort4*)&R[row * RSTRIDE + lcol];
                *(ushort4*)&Gout[(size_t)(off + gr) * N + nt * 64 + lcol] = v;
            }
        }
    } else {
        float* Yz = Yout + (size_t)blockIdx.z * NPOS * N;
        #pragma unroll
        for (int ni = 0; ni < 4; ++ni) {
            int col = nt * 64 + ni * 16 + l16;
            float bv = (blockIdx.z == 0) ? bias[col] : 0.f;
            #pragma unroll
            for (int mi = 0; mi < 2; ++mi) {
                #pragma unroll
                for (int r = 0; r < 4; ++r) {
                    int lm = mt * 128 + wave * 32 + mi * 16 + quad * 4 + r;
                    if (lm < cnt)
                        Yz[(size_t)(off + lm) * N + col] = acc[mi][ni][r] + bv;
                }
            }
        }
    }
}

// ---------------- combine: out[tok] = sum_z Y[z][posC] + dropped * sum_z Y[z][posU]
__global__ void __launch_bounds__(192) combine_kernel(
    const float* __restrict__ Y, const int* __restrict__ invC,
    const int* __restrict__ invU, const int* __restrict__ dropped,
    float* __restrict__ out)
{
    int tok = blockIdx.x, t = threadIdx.x;
    const float* Y0 = Y;
    const float* Y1 = Y + (size_t)NPOS * HDIM;
    int pc = invC[tok];
    float4 a = *(const float4*)(Y0 + (size_t)pc * HDIM + t * 4);
    float4 b = *(const float4*)(Y1 + (size_t)pc * HDIM + t * 4);
    float4 o;
    o.x = a.x + b.x; o.y = a.y + b.y; o.z = a.z + b.z; o.w = a.w + b.w;
    if (dropped[tok]) {
        int pu = invU[tok];
        float4 c = *(const float4*)(Y0 + (size_t)pu * HDIM + t * 4);
        float4 d = *(const float4*)(Y1 + (size_t)pu * HDIM + t * 4);
        o.x += c.x + d.x; o.y += c.y + d.y; o.z += c.z + d.z; o.w += c.w + d.w;
    }
    *(float4*)(out + (size_t)tok * HDIM + t * 4) = o;
}

extern "C" void kernel_launch(void* const* d_in, const int* in_sizes, int n_in,
                              void* d_out, int out_size, void* d_ws, size_t ws_size,
                              hipStream_t stream) {
    (void)in_sizes; (void)n_in; (void)out_size; (void)ws_size;
    const float* h   = (const float*)d_in[0];
    const float* Wsc = (const float*)d_in[1];
    const float* bsc = (const float*)d_in[2];
    const float* W1c = (const float*)d_in[3];
    const float* b1c = (const float*)d_in[4];
    const float* W2c = (const float*)d_in[5];
    const float* b2c = (const float*)d_in[6];
    const float* Wsu = (const float*)d_in[7];
    const float* bsu = (const float*)d_in[8];
    const float* W1u = (const float*)d_in[9];
    const float* b1u = (const float*)d_in[10];
    const float* W2u = (const float*)d_in[11];
    const float* b2u = (const float*)d_in[12];
    float* out = (float*)d_out;

    char* w = (char*)d_ws;
    size_t o = 0;
    auto carve = [&](size_t bytes) -> char* {
        char* p = w + o; o += (bytes + 255) & ~(size_t)255; return p;
    };
    int*   route_c = (int*)carve(NTOK * 4);
    unsigned long long* key = (unsigned long long*)carve(NTOK * 8);
    int*   route_u = (int*)carve(NTOK * 4);
    int*   rankC   = (int*)carve(NTOK * 4);
    int*   dropped = (int*)carve(NTOK * 4);
    int*   offAll  = (int*)carve(9 * 4);
    int*   cur     = (int*)carve(8 * 4);
    int*   ntot    = (int*)carve(4);
    int*   perm    = (int*)carve(NPOS * 4);
    int*   invC    = (int*)carve(NTOK * 4);
    int*   invU    = (int*)carve(NTOK * 4);
    int*   tab     = (int*)carve(MAXT * 2 * 4);
    unsigned short* X   = (unsigned short*)carve((size_t)NPOS * HDIM * 2);
    unsigned short* G   = (unsigned short*)carve((size_t)NPOS * FDIM * 2);
    float*          Y2  = (float*)carve((size_t)2 * NPOS * HDIM * 4);
    unsigned short* BtA = (unsigned short*)carve((size_t)8 * HDIM * FDIM * 2);
    unsigned short* BtB = (unsigned short*)carve((size_t)8 * FDIM * HDIM * 2);

    int capacity = NTOK / NEXP;   // int(1.0 * 4096 / 4) = 1024

    route_kernel<<<NTOK/4, 256, 0, stream>>>(h, Wsc, bsc, Wsu, bsu,
                                             route_c, key, route_u);
    rank_kernel<<<NTOK/16, 256, 0, stream>>>(key, rankC, dropped, capacity);
    offsets_kernel<<<1, 256, 0, stream>>>(route_c, route_u, dropped,
                                          offAll, cur, tab, ntot);
    scatter_kernel<<<NTOK/256, 256, 0, stream>>>(route_c, route_u, dropped, rankC,
                                                 offAll, cur, perm, invC, invU);
    gather_kernel<<<NPOS, 192, 0, stream>>>(h, perm, ntot, X);

    // transpose+convert weights to bf16 [8][N][K] (c experts z<4, u experts z>=4)
    wtrans_kernel<<<dim3(FDIM/64, HDIM/128, 8), 256, 0, stream>>>(W1c, W1u, BtA, HDIM, FDIM);
    wtrans_kernel<<<dim3(HDIM/64, FDIM/128, 8), 256, 0, stream>>>(W2c, W2u, BtB, FDIM, HDIM);

    // FFN1 over 8 groups: X @ W1 -> GELU -> G (bf16, position-indexed)
    ffn_gemm<<<dim3(FDIM/64, MAXT, 1), 256, 0, stream>>>(
        X, BtA, b1c, b1u, offAll, tab, G, nullptr, HDIM, FDIM, 1);
    // FFN2: G @ W2 -> Y2[z][pos][H] (fp32 slabs, split-K=2, no atomics)
    ffn_gemm<<<dim3(HDIM/64, MAXT, 2), 256, 0, stream>>>(
        G, BtB, b2c, b2u, offAll, tab, nullptr, Y2, FDIM, HDIM, 0);
    // out[tok] = sum of slabs at common pos (+ unique pos if dropped)
    combine_kernel<<<NTOK, 192, 0, stream>>>(Y2, invC, invU, dropped, out);
}

// Round 3
// 332.231 us; speedup vs baseline: 1.2220x; 1.0239x over previous
//
#include <hip/hip_runtime.h>
#include <hip/hip_bf16.h>
#include <math.h>

#define NTOK 4096
#define HDIM 768
#define FDIM 3072
#define NEXP 4
#define MAXU 3072            // worst-case dropped tokens
#define MAXT 64              // worst-case (expert,mtile) tiles across 8 groups
#define NPOS (NTOK + MAXU)
#define RSTRIDE 76           // repack LDS row stride (shorts): quad bank-bases disjoint

typedef __attribute__((ext_vector_type(4))) float f32x4;
typedef __attribute__((ext_vector_type(8))) short s16x8;

__device__ __forceinline__ unsigned short f2bf(float f) {
    union { float f; unsigned int u; } v; v.f = f;
    unsigned int u = v.u;
    unsigned int r = (u + 0x7fffu + ((u >> 16) & 1u)) >> 16;
    return (unsigned short)r;
}

// async global->LDS, 16B per lane. lds dst is wave-uniform; HW adds lane*16.
__device__ __forceinline__ void gload_lds16(const unsigned short* g, unsigned short* l) {
    __builtin_amdgcn_global_load_lds((const __attribute__((address_space(1))) void*)g,
                                     (__attribute__((address_space(3))) void*)l, 16, 0, 0);
}

// ---------------- routing: one wave per token ------------------------------------
// writes 64-bit sort key: (expert << 32) | float_bits(pmax). pmax in (0,1] so the
// bit pattern is monotonic and bit-equality == float-equality (exact tie semantics).
__global__ void __launch_bounds__(256) route_kernel(
    const float* __restrict__ h, const float* __restrict__ Wsc, const float* __restrict__ bsc,
    const float* __restrict__ Wsu, const float* __restrict__ bsu,
    int* __restrict__ route_c, unsigned long long* __restrict__ key,
    int* __restrict__ route_u)
{
    int tok = blockIdx.x * 4 + (threadIdx.x >> 6);
    int lane = threadIdx.x & 63;
    const float* hr = h + (size_t)tok * HDIM;
    float ac[4] = {0.f,0.f,0.f,0.f}, au[4] = {0.f,0.f,0.f,0.f};
    for (int k = lane; k < HDIM; k += 64) {
        float x = hr[k];
        const float4 wc = *(const float4*)(Wsc + k * 4);
        const float4 wu = *(const float4*)(Wsu + k * 4);
        ac[0] += x * wc.x; ac[1] += x * wc.y; ac[2] += x * wc.z; ac[3] += x * wc.w;
        au[0] += x * wu.x; au[1] += x * wu.y; au[2] += x * wu.z; au[3] += x * wu.w;
    }
    #pragma unroll
    for (int off = 32; off > 0; off >>= 1) {
        #pragma unroll
        for (int j = 0; j < 4; ++j) {
            ac[j] += __shfl_xor(ac[j], off);
            au[j] += __shfl_xor(au[j], off);
        }
    }
    if (lane == 0) {
        float lc[4], lu[4];
        #pragma unroll
        for (int j = 0; j < 4; ++j) { lc[j] = ac[j] + bsc[j]; lu[j] = au[j] + bsu[j]; }
        int bc = 0; float mc = lc[0];
        #pragma unroll
        for (int j = 1; j < 4; ++j) if (lc[j] > mc) { mc = lc[j]; bc = j; }
        float dc = 0.f;
        #pragma unroll
        for (int j = 0; j < 4; ++j) dc += expf(lc[j] - mc);
        float p = 1.0f / dc;
        union { float f; unsigned int u; } pv; pv.f = p;
        route_c[tok] = bc;
        key[tok] = ((unsigned long long)(unsigned int)bc << 32) | (unsigned long long)pv.u;
        int bu = 0; float mu = lu[0];
        #pragma unroll
        for (int j = 1; j < 4; ++j) if (lu[j] > mu) { mu = lu[j]; bu = j; }
        route_u[tok] = bu;
    }
}

// ------- rank within expert group by (-pmax, index) ------------------------------
// LDS-staged branch-free scan. cnt = #{same-expert tokens with higher priority}
// is a collision-free position within the expert group (strict total order),
// so it doubles as the scatter position -> NO global atomics anywhere here.
__global__ void __launch_bounds__(256) rank_kernel(
    const unsigned long long* __restrict__ key,
    int* __restrict__ rankC, int* __restrict__ dropped, int capacity)
{
    __shared__ unsigned long long lkey[NTOK];
    int tid = threadIdx.x;
    int wave = tid >> 6, lane = tid & 63;

    // stage key array into LDS (16B per thread per iter, coalesced)
    const ulonglong2* k2 = (const ulonglong2*)key;
    ulonglong2* l2 = (ulonglong2*)lkey;
    #pragma unroll
    for (int j = 0; j < NTOK / 2 / 256; ++j)
        l2[tid + j * 256] = k2[tid + j * 256];

    int t0 = blockIdx.x * 16 + wave * 4;      // 4 tokens per wave
    unsigned long long ki[4];
    int cnt[4] = {0, 0, 0, 0};
    #pragma unroll
    for (int t = 0; t < 4; ++t) ki[t] = key[t0 + t];

    __syncthreads();

    for (int it = 0; it < NTOK / 64; ++it) {
        int j = lane + it * 64;
        unsigned long long kj = lkey[j];
        #pragma unroll
        for (int t = 0; t < 4; ++t) {
            bool same = ((kj ^ ki[t]) >> 32) == 0;                      // same expert
            bool hi = (kj > ki[t]) || ((kj == ki[t]) && (j < t0 + t));  // higher priority
            cnt[t] += (same && hi) ? 1 : 0;
        }
    }
    #pragma unroll
    for (int off = 32; off > 0; off >>= 1) {
        #pragma unroll
        for (int t = 0; t < 4; ++t) cnt[t] += __shfl_xor(cnt[t], off);
    }
    if (lane == 0) {
        #pragma unroll
        for (int t = 0; t < 4; ++t) {
            int i = t0 + t;
            rankC[i] = cnt[t];
            dropped[i] = (cnt[t] >= capacity) ? 1 : 0;
        }
    }
}

// --------- fused histogram + offsets + tile table (one 256-thread block) ---------
// register histogram (branch-free), wave shuffle-reduce, 32 LDS atomics total.
__global__ void __launch_bounds__(256) offsets_kernel(
    const int* __restrict__ rc, const int* __restrict__ ru, const int* __restrict__ dropped,
    int* __restrict__ offAll,  // 9
    int* __restrict__ cur,     // 8
    int* __restrict__ tab,     // MAXT*2
    int* __restrict__ ntot)
{
    __shared__ int sc[8];
    int tid = threadIdx.x;
    if (tid < 8) sc[tid] = 0;
    int c0=0,c1=0,c2=0,c3=0,c4=0,c5=0,c6=0,c7=0;
    #pragma unroll
    for (int j = 0; j < NTOK / 256; ++j) {
        int i = tid + j * 256;
        int e = rc[i];
        c0 += (e == 0); c1 += (e == 1); c2 += (e == 2); c3 += (e == 3);
        int d = dropped[i];
        int eu = ru[i];
        c4 += d & (eu == 0); c5 += d & (eu == 1);
        c6 += d & (eu == 2); c7 += d & (eu == 3);
    }
    #pragma unroll
    for (int off = 32; off > 0; off >>= 1) {
        c0 += __shfl_xor(c0, off); c1 += __shfl_xor(c1, off);
        c2 += __shfl_xor(c2, off); c3 += __shfl_xor(c3, off);
        c4 += __shfl_xor(c4, off); c5 += __shfl_xor(c5, off);
        c6 += __shfl_xor(c6, off); c7 += __shfl_xor(c7, off);
    }
    __syncthreads();
    if ((tid & 63) == 0) {
        atomicAdd(&sc[0], c0); atomicAdd(&sc[1], c1);
        atomicAdd(&sc[2], c2); atomicAdd(&sc[3], c3);
        atomicAdd(&sc[4], c4); atomicAdd(&sc[5], c5);
        atomicAdd(&sc[6], c6); atomicAdd(&sc[7], c7);
    }
    __syncthreads();
    if (tid == 0) {
        int o = 0;
        for (int e = 0; e < 8; ++e) { offAll[e] = o; o += sc[e]; }
        offAll[8] = o;
        *ntot = o;
        for (int j = 0; j < 8; ++j) cur[j] = 0;
        int t = 0;
        for (int e = 0; e < 8; ++e) {
            int nt = (sc[e] + 127) >> 7;
            for (int m = 0; m < nt && t < MAXT; ++m) { tab[t*2] = e; tab[t*2+1] = m; ++t; }
        }
        for (; t < MAXT; ++t) { tab[t*2] = -1; tab[t*2+1] = 0; }
    }
}

// ----- scatter: common position is deterministic (offAll[e] + rank) -------------
// atomics only for dropped tokens (~tens) -> negligible contention.
__global__ void __launch_bounds__(256) scatter_kernel(
    const int* __restrict__ rc, const int* __restrict__ ru, const int* __restrict__ dropped,
    const int* __restrict__ rankC,
    const int* __restrict__ offAll, int* __restrict__ cur, int* __restrict__ perm,
    int* __restrict__ invC, int* __restrict__ invU)
{
    int i = blockIdx.x * 256 + threadIdx.x;
    if (i >= NTOK) return;
    int e = rc[i];
    int p = offAll[e] + rankC[i];
    perm[p] = i;
    invC[i] = p;
    if (dropped[i]) {
        int eu = 4 + ru[i];
        int q = offAll[eu] + atomicAdd(&cur[eu], 1);
        perm[q] = i;
        invU[i] = q;
    }
}

// ---------------- gather tokens (sorted order) into bf16 -------------------------
__global__ void __launch_bounds__(192) gather_kernel(
    const float* __restrict__ h, const int* __restrict__ perm,
    const int* __restrict__ ntot, unsigned short* __restrict__ Xs)
{
    int pos = blockIdx.x;
    if (pos >= *ntot) return;
    int t = threadIdx.x;
    int tok = perm[pos];
    const float4 v = *(const float4*)(h + (size_t)tok * HDIM + t * 4);
    ushort4 o;
    o.x = f2bf(v.x); o.y = f2bf(v.y); o.z = f2bf(v.z); o.w = f2bf(v.w);
    *(ushort4*)(Xs + (size_t)pos * HDIM + t * 4) = o;
}

// ------- weight transpose+convert: fp32 [4][K][N] x2 -> bf16 [8][N][K] -----------
// 128k x 64n tile: reads float4 coalesced, writes 256-B contiguous k-segments.
__global__ void __launch_bounds__(256) wtrans_kernel(
    const float* __restrict__ Wc, const float* __restrict__ Wu,
    unsigned short* __restrict__ Bt, int K, int N)
{
    int z = blockIdx.z;   // 0..7
    const float* We = (z < 4) ? (Wc + (size_t)z * K * N)
                              : (Wu + (size_t)(z - 4) * K * N);
    unsigned short* Be = Bt + (size_t)z * N * K;
    int k0 = blockIdx.y * 128, n0 = blockIdx.x * 64;
    __shared__ float t[128][65];
    int tid = threadIdx.x;
    int rr = tid >> 4, c4 = (tid & 15) * 4;   // 16 float4 per 64-float row
    #pragma unroll
    for (int i = 0; i < 8; ++i) {
        int row = rr + i * 16;
        const float4 v = *(const float4*)(We + (size_t)(k0 + row) * N + n0 + c4);
        t[row][c4+0] = v.x; t[row][c4+1] = v.y; t[row][c4+2] = v.z; t[row][c4+3] = v.w;
    }
    __syncthreads();
    #pragma unroll
    for (int i = 0; i < 8; ++i) {
        int idx = tid + i * 256;
        int n = idx >> 5, kk = (idx & 31) * 4;   // 32 ushort4 per 128-k row
        ushort4 o;
        o.x = f2bf(t[kk+0][n]); o.y = f2bf(t[kk+1][n]);
        o.z = f2bf(t[kk+2][n]); o.w = f2bf(t[kk+3][n]);
        *(ushort4*)(Be + (size_t)(n0 + n) * K + k0 + kk) = o;
    }
}

// ---------------- grouped GEMM over 8 groups, 128(M)x128(N), BK=64 ---------------
// LDS staging via global_load_lds, 3-bit XOR chunk swizzle; 4 waves in 2x2 grid,
// each wave owns a 64x64 output tile (acc 4x4 of 16x16 frags).
//  doGelu=1: GELU -> bf16 repack (two 32-row halves, wave-private LDS reuse) ->
//            ushort4 stores to Gout[pos]
//  doGelu=0: fp32 stores into per-z slab Yout[z][pos][N] (no atomics)
__global__ void __launch_bounds__(256, 3) ffn_gemm(
    const unsigned short* __restrict__ A, const unsigned short* __restrict__ Bt,
    const float* __restrict__ biasC, const float* __restrict__ biasU,
    const int* __restrict__ offs, const int* __restrict__ tab,
    unsigned short* __restrict__ Gout, float* __restrict__ Yout,
    int K, int N, int doGelu)
{
    int e = tab[blockIdx.y * 2];
    if (e < 0) return;
    int mt = tab[blockIdx.y * 2 + 1];
    int off = offs[e];
    int cnt = offs[e + 1] - off;
    if (mt * 128 >= cnt) return;
    int nt = blockIdx.x;
    int klen = K / gridDim.z;
    int kbeg = blockIdx.z * klen;

    // LDS: As 128r x 64k bf16 = [0,8192) shorts; Bs 128r x 64k = [8192,16384).
    // chunk (row,s) s=0..7 holds global k-seg (s ^ (row&7)); chunk c at base c*8.
    // FFN1 epilogue repack reuses [0, 4*32*RSTRIDE)=9728 shorts (wave-private).
    __shared__ unsigned short lds[16384];
    unsigned short* As = lds;
    unsigned short* Bs = lds + 8192;

    int tid = threadIdx.x;
    int lane = tid & 63, wave = tid >> 6;
    int quad = lane >> 4, l16 = lane & 15;
    int wr = wave >> 1, wc = wave & 1;        // 2x2 wave grid, 64x64 per wave

    f32x4 acc[4][4];
    #pragma unroll
    for (int a = 0; a < 4; ++a)
        #pragma unroll
        for (int b = 0; b < 4; ++b)
            acc[a][b] = (f32x4){0.f, 0.f, 0.f, 0.f};

    const unsigned short* Ae = A + (size_t)off * K;
    const unsigned short* Be = Bt + ((size_t)e * N + (size_t)nt * 128) * K;

    // A: 1024 chunks, 4 per thread; B: 1024 chunks, 4 per thread
    const unsigned short* asrc[4]; unsigned short* adst[4];
    const unsigned short* bsrc[4]; unsigned short* bdst[4];
    #pragma unroll
    for (int j = 0; j < 4; ++j) {
        int c = tid + j * 256;
        int row = c >> 3, s = c & 7;
        int gseg = (s ^ (row & 7)) * 8;
        int ar = mt * 128 + row; if (ar >= cnt) ar = cnt - 1;
        asrc[j] = Ae + (size_t)ar * K + kbeg + gseg;
        adst[j] = &As[(j * 256 + wave * 64) * 8];   // wave-uniform; HW adds lane*16B
        bsrc[j] = Be + (size_t)row * K + kbeg + gseg;
        bdst[j] = &Bs[(j * 256 + wave * 64) * 8];
    }

    for (int k0 = 0; k0 < klen; k0 += 64) {
        #pragma unroll
        for (int j = 0; j < 4; ++j) gload_lds16(asrc[j] + k0, adst[j]);
        #pragma unroll
        for (int j = 0; j < 4; ++j) gload_lds16(bsrc[j] + k0, bdst[j]);
        __syncthreads();

        #pragma unroll
        for (int ks = 0; ks < 2; ++ks) {
            int cc = ((ks * 4 + quad) ^ (l16 & 7)) * 8;
            s16x8 af[4], bf[4];
            #pragma unroll
            for (int mi = 0; mi < 4; ++mi)
                af[mi] = *(const s16x8*)&As[(wr * 64 + mi * 16 + l16) * 64 + cc];
            #pragma unroll
            for (int ni = 0; ni < 4; ++ni)
                bf[ni] = *(const s16x8*)&Bs[(wc * 64 + ni * 16 + l16) * 64 + cc];
            #pragma unroll
            for (int mi = 0; mi < 4; ++mi)
                #pragma unroll
                for (int ni = 0; ni < 4; ++ni)
                    acc[mi][ni] = __builtin_amdgcn_mfma_f32_16x16x32_bf16(af[mi], bf[ni], acc[mi][ni], 0, 0, 0);
        }
        __syncthreads();
    }

    const float* bias = (e < 4) ? (biasC + (size_t)e * N) : (biasU + (size_t)(e - 4) * N);

    if (doGelu) {
        // GELU + bf16, repack 64x64 wave tile in two 32-row halves via wave-private
        // LDS (reuses GEMM staging space; all waves past final barrier), 8B stores.
        unsigned short* R = lds + wave * (32 * RSTRIDE);
        int lrow = lane >> 4, lcol = (lane & 15) * 4;
        #pragma unroll
        for (int h = 0; h < 2; ++h) {
            if (h) __builtin_amdgcn_s_waitcnt(0);   // half-0 reads of R complete
            #pragma unroll
            for (int ni = 0; ni < 4; ++ni) {
                float bv = bias[nt * 128 + wc * 64 + ni * 16 + l16];
                #pragma unroll
                for (int mi2 = 0; mi2 < 2; ++mi2) {
                    int mi = h * 2 + mi2;
                    #pragma unroll
                    for (int r = 0; r < 4; ++r) {
                        float x = acc[mi][ni][r] + bv;
                        x = 0.5f * x * (1.0f + erff(x * 0.70710678118654752440f));
                        R[(mi2 * 16 + quad * 4 + r) * RSTRIDE + ni * 16 + l16] = f2bf(x);
                    }
                }
            }
            __builtin_amdgcn_s_waitcnt(0);  // wave-private region: no barrier needed
            #pragma unroll
            for (int p = 0; p < 8; ++p) {
                int row = p * 4 + lrow;
                int gr = mt * 128 + wr * 64 + h * 32 + row;
                if (gr < cnt) {
                    ushort4 v = *(const ushort4*)&R[row * RSTRIDE + lcol];
                    *(ushort4*)&Gout[(size_t)(off + gr) * N + nt * 128 + wc * 64 + lcol] = v;
                }
            }
        }
    } else {
        float* Yz = Yout + (size_t)blockIdx.z * NPOS * N;
        #pragma unroll
        for (int ni = 0; ni < 4; ++ni) {
            int col = nt * 128 + wc * 64 + ni * 16 + l16;
            float bv = (blockIdx.z == 0) ? bias[col] : 0.f;
            #pragma unroll
            for (int mi = 0; mi < 4; ++mi) {
                #pragma unroll
                for (int r = 0; r < 4; ++r) {
                    int lm = mt * 128 + wr * 64 + mi * 16 + quad * 4 + r;
                    if (lm < cnt)
                        Yz[(size_t)(off + lm) * N + col] = acc[mi][ni][r] + bv;
                }
            }
        }
    }
}

// ---------------- combine: out[tok] = sum_z Y[z][posC] + dropped * sum_z Y[z][posU]
__global__ void __launch_bounds__(192) combine_kernel(
    const float* __restrict__ Y, const int* __restrict__ invC,
    const int* __restrict__ invU, const int* __restrict__ dropped,
    float* __restrict__ out)
{
    int tok = blockIdx.x, t = threadIdx.x;
    const float* Y0 = Y;
    const float* Y1 = Y + (size_t)NPOS * HDIM;
    int pc = invC[tok];
    float4 a = *(const float4*)(Y0 + (size_t)pc * HDIM + t * 4);
    float4 b = *(const float4*)(Y1 + (size_t)pc * HDIM + t * 4);
    float4 o;
    o.x = a.x + b.x; o.y = a.y + b.y; o.z = a.z + b.z; o.w = a.w + b.w;
    if (dropped[tok]) {
        int pu = invU[tok];
        float4 c = *(const float4*)(Y0 + (size_t)pu * HDIM + t * 4);
        float4 d = *(const float4*)(Y1 + (size_t)pu * HDIM + t * 4);
        o.x += c.x + d.x; o.y += c.y + d.y; o.z += c.z + d.z; o.w += c.w + d.w;
    }
    *(float4*)(out + (size_t)tok * HDIM + t * 4) = o;
}

extern "C" void kernel_launch(void* const* d_in, const int* in_sizes, int n_in,
                              void* d_out, int out_size, void* d_ws, size_t ws_size,
                              hipStream_t stream) {
    (void)in_sizes; (void)n_in; (void)out_size; (void)ws_size;
    const float* h   = (const float*)d_in[0];
    const float* Wsc = (const float*)d_in[1];
    const float* bsc = (const float*)d_in[2];
    const float* W1c = (const float*)d_in[3];
    const float* b1c = (const float*)d_in[4];
    const float* W2c = (const float*)d_in[5];
    const float* b2c = (const float*)d_in[6];
    const float* Wsu = (const float*)d_in[7];
    const float* bsu = (const float*)d_in[8];
    const float* W1u = (const float*)d_in[9];
    const float* b1u = (const float*)d_in[10];
    const float* W2u = (const float*)d_in[11];
    const float* b2u = (const float*)d_in[12];
    float* out = (float*)d_out;

    char* w = (char*)d_ws;
    size_t o = 0;
    auto carve = [&](size_t bytes) -> char* {
        char* p = w + o; o += (bytes + 255) & ~(size_t)255; return p;
    };
    int*   route_c = (int*)carve(NTOK * 4);
    unsigned long long* key = (unsigned long long*)carve(NTOK * 8);
    int*   route_u = (int*)carve(NTOK * 4);
    int*   rankC   = (int*)carve(NTOK * 4);
    int*   dropped = (int*)carve(NTOK * 4);
    int*   offAll  = (int*)carve(9 * 4);
    int*   cur     = (int*)carve(8 * 4);
    int*   ntot    = (int*)carve(4);
    int*   perm    = (int*)carve(NPOS * 4);
    int*   invC    = (int*)carve(NTOK * 4);
    int*   invU    = (int*)carve(NTOK * 4);
    int*   tab     = (int*)carve(MAXT * 2 * 4);
    unsigned short* X   = (unsigned short*)carve((size_t)NPOS * HDIM * 2);
    unsigned short* G   = (unsigned short*)carve((size_t)NPOS * FDIM * 2);
    float*          Y2  = (float*)carve((size_t)2 * NPOS * HDIM * 4);
    unsigned short* BtA = (unsigned short*)carve((size_t)8 * HDIM * FDIM * 2);
    unsigned short* BtB = (unsigned short*)carve((size_t)8 * FDIM * HDIM * 2);

    int capacity = NTOK / NEXP;   // int(1.0 * 4096 / 4) = 1024

    route_kernel<<<NTOK/4, 256, 0, stream>>>(h, Wsc, bsc, Wsu, bsu,
                                             route_c, key, route_u);
    rank_kernel<<<NTOK/16, 256, 0, stream>>>(key, rankC, dropped, capacity);
    offsets_kernel<<<1, 256, 0, stream>>>(route_c, route_u, dropped,
                                          offAll, cur, tab, ntot);
    scatter_kernel<<<NTOK/256, 256, 0, stream>>>(route_c, route_u, dropped, rankC,
                                                 offAll, cur, perm, invC, invU);
    gather_kernel<<<NPOS, 192, 0, stream>>>(h, perm, ntot, X);

    // transpose+convert weights to bf16 [8][N][K] (c experts z<4, u experts z>=4)
    wtrans_kernel<<<dim3(FDIM/64, HDIM/128, 8), 256, 0, stream>>>(W1c, W1u, BtA, HDIM, FDIM);
    wtrans_kernel<<<dim3(HDIM/64, FDIM/128, 8), 256, 0, stream>>>(W2c, W2u, BtB, FDIM, HDIM);

    // FFN1 over 8 groups: X @ W1 -> GELU -> G (bf16, position-indexed)
    ffn_gemm<<<dim3(FDIM/128, MAXT, 1), 256, 0, stream>>>(
        X, BtA, b1c, b1u, offAll, tab, G, nullptr, HDIM, FDIM, 1);
    // FFN2: G @ W2 -> Y2[z][pos][H] (fp32 slabs, split-K=2, no atomics)
    ffn_gemm<<<dim3(HDIM/128, MAXT, 2), 256, 0, stream>>>(
        G, BtB, b2c, b2u, offAll, tab, nullptr, Y2, FDIM, HDIM, 0);
    // out[tok] = sum of slabs at common pos (+ unique pos if dropped)
    combine_kernel<<<NTOK, 192, 0, stream>>>(Y2, invC, invU, dropped, out);
}